// Round 1
// baseline (657.240 us; speedup 1.0000x reference)
//
#include <hip/hip_runtime.h>
#include <cstdint>
#include <cstddef>

#define INF    4096
#define OUTF   4096
#define NTOK   8192
#define TOPK   128

// Compact per-row top-k tables, transposed for coalesced reads in the apply
// kernel: entry (k, o) at [k*OUTF + o]. Stored in device globals so we do not
// depend on ws_size; kernel A fully rewrites every slot on every call (the
// harness re-poisons buffers between launches, so no state may be assumed).
__device__ float          g_wt[TOPK * OUTF];
__device__ unsigned short g_it[TOPK * OUTF];

// ---------------------------------------------------------------------------
// Kernel A: exact per-row top-128 of |w| with reference-matching tie breaking
// (value desc, index asc — jax.lax.top_k keeps the lower index on ties).
// One block per output row, 256 threads x 16 elements.
// ---------------------------------------------------------------------------
__global__ __launch_bounds__(256) void topk_select(const float* __restrict__ weight) {
  const int o   = blockIdx.x;
  const int tid = threadIdx.x;

  __shared__ unsigned int   bins[2048];
  __shared__ unsigned int   csum[256];
  __shared__ unsigned int   scnt[256];
  __shared__ unsigned int   cand_val[1024];
  __shared__ unsigned short cand_idx[1024];
  __shared__ unsigned short chosen[TOPK];
  __shared__ unsigned int   s_info[3];   // 0: ncand, 1: bracket bin, 2: need

  // Load this thread's 16 contiguous weights (coalesced float4).
  float wv[16];
  const float* wrow = weight + (size_t)o * INF;
  #pragma unroll
  for (int j = 0; j < 4; ++j) {
    float4 v = *reinterpret_cast<const float4*>(wrow + tid * 16 + j * 4);
    wv[j * 4 + 0] = v.x; wv[j * 4 + 1] = v.y;
    wv[j * 4 + 2] = v.z; wv[j * 4 + 3] = v.w;
  }

  #pragma unroll
  for (int j = 0; j < 8; ++j) bins[tid + j * 256] = 0;
  if (tid == 0) s_info[0] = 0;
  __syncthreads();

  // Histogram of |w| over 2048 bins on [0, 1/64). x * 2^17 is exact (pure
  // exponent shift) -> strictly monotone binning, no boundary inversions.
  #pragma unroll
  for (int j = 0; j < 16; ++j) {
    int b = (int)(fabsf(wv[j]) * 131072.0f);
    b = b > 2047 ? 2047 : b;
    atomicAdd(&bins[b], 1u);
  }
  __syncthreads();

  unsigned int cs = 0;
  #pragma unroll
  for (int j = 0; j < 8; ++j) cs += bins[tid * 8 + j];
  csum[tid] = cs;
  __syncthreads();

  // Find bracket bin B: largest bin with suffix count >= TOPK.
  if (tid == 0) {
    unsigned int acc = 0, above = 0; int B = 0;
    for (int c = 255; c >= 0; --c) {
      if (acc + csum[c] >= TOPK) {
        for (int j = c * 8 + 7; ; --j) {
          if (acc + bins[j] >= TOPK) { B = j; above = acc; break; }
          acc += bins[j];
        }
        break;
      }
      acc += csum[c];
    }
    s_info[1] = (unsigned int)B;
    s_info[2] = TOPK - above;       // how many to take from the bracket bin
  }
  __syncthreads();

  const int          B    = (int)s_info[1];
  const unsigned int need = s_info[2];

  // Collect bracket-bin candidates (expected ~2 per row; capped generously).
  #pragma unroll
  for (int j = 0; j < 16; ++j) {
    int b = (int)(fabsf(wv[j]) * 131072.0f);
    b = b > 2047 ? 2047 : b;
    if (b == B) {
      unsigned int p = atomicAdd(&s_info[0], 1u);
      if (p < 1024u) {
        cand_val[p] = __float_as_uint(fabsf(wv[j]));
        cand_idx[p] = (unsigned short)(tid * 16 + j);
      }
    }
  }
  __syncthreads();

  // Tiny insertion sort by (|w| desc, idx asc); take first `need`.
  if (tid == 0) {
    int n = s_info[0] < 1024u ? (int)s_info[0] : 1024;
    for (int a = 1; a < n; ++a) {
      unsigned int v = cand_val[a]; unsigned short id = cand_idx[a];
      int p = a - 1;
      while (p >= 0 && (cand_val[p] < v || (cand_val[p] == v && cand_idx[p] > id))) {
        cand_val[p + 1] = cand_val[p]; cand_idx[p + 1] = cand_idx[p]; --p;
      }
      cand_val[p + 1] = v; cand_idx[p + 1] = id;
    }
    int m = (int)need < n ? (int)need : n;
    for (int j = 0; j < m; ++j) chosen[j] = cand_idx[j];
  }
  __syncthreads();

  // Selection flags + per-thread counts (index order preserved).
  unsigned int mask = 0, cnt = 0;
  #pragma unroll
  for (int j = 0; j < 16; ++j) {
    int b = (int)(fabsf(wv[j]) * 131072.0f);
    b = b > 2047 ? 2047 : b;
    bool sel = (b > B);
    if (b == B) {
      unsigned short idx = (unsigned short)(tid * 16 + j);
      for (unsigned int q = 0; q < need; ++q)
        if (chosen[q] == idx) { sel = true; break; }
    }
    if (sel) { mask |= 1u << j; ++cnt; }
  }
  scnt[tid] = cnt;
  __syncthreads();
  if (tid == 0) {                       // exclusive scan -> deterministic slots
    unsigned int run = 0;
    for (int t = 0; t < 256; ++t) { unsigned int c = scnt[t]; scnt[t] = run; run += c; }
  }
  __syncthreads();

  unsigned int slot = scnt[tid];
  #pragma unroll
  for (int j = 0; j < 16; ++j) {
    if (mask & (1u << j)) {
      g_wt[slot * OUTF + o] = wv[j];                       // exact f32 weight
      g_it[slot * OUTF + o] = (unsigned short)(tid * 16 + j);
      ++slot;
    }
  }
}

// ---------------------------------------------------------------------------
// Kernel B: y[t, o] = bias[o] + sum_k wt[k][o] * x[t, it[k][o]]
// Block = 8 tokens staged feature-major in LDS (two [4096][4] f32 arrays,
// 128 KB), 1024 threads; thread = one output per chunk, 128-step k-loop with
// coalesced table loads and two 16B-aligned ds_read_b128 gathers.
// ---------------------------------------------------------------------------
__global__ __launch_bounds__(1024) void spmm8(const float* __restrict__ x,
                                              const float* __restrict__ bias,
                                              float* __restrict__ y) {
  __shared__ float xa[INF * 4];   // tokens t0+0..3, layout [feature][token]
  __shared__ float xb[INF * 4];   // tokens t0+4..7

  const int tid = threadIdx.x;
  const int t0  = blockIdx.x * 8;

  // Stage x tile: feature-major transpose. Write banks = (4c + t) % 32 over
  // 8 consecutive c and 8 t -> all 32 banks, 2-way alias (free per m136).
  for (int r = tid; r < 8 * INF; r += 1024) {
    int c = r >> 3;
    int t = r & 7;
    float v = x[(size_t)(t0 + t) * INF + c];
    ((t < 4) ? xa : xb)[c * 4 + (t & 3)] = v;
  }
  __syncthreads();

  #pragma unroll 1
  for (int chunk = 0; chunk < 4; ++chunk) {
    const int o = (chunk << 10) + tid;
    const float*          wq = g_wt + o;
    const unsigned short* iq = g_it + o;
    float4 A  = {0.f, 0.f, 0.f, 0.f};
    float4 Bv = {0.f, 0.f, 0.f, 0.f};

    #pragma unroll 4
    for (int k = 0; k < TOPK; ++k) {
      float w = *wq;            // wt[k][o]: lanes read consecutive o -> coalesced
      int   i = (int)*iq;
      wq += OUTF; iq += OUTF;
      float4 a = *reinterpret_cast<const float4*>(&xa[i << 2]);
      float4 b = *reinterpret_cast<const float4*>(&xb[i << 2]);
      A.x  = fmaf(w, a.x, A.x);  A.y  = fmaf(w, a.y, A.y);
      A.z  = fmaf(w, a.z, A.z);  A.w  = fmaf(w, a.w, A.w);
      Bv.x = fmaf(w, b.x, Bv.x); Bv.y = fmaf(w, b.y, Bv.y);
      Bv.z = fmaf(w, b.z, Bv.z); Bv.w = fmaf(w, b.w, Bv.w);
    }

    const float bb = bias[o];
    y[(size_t)(t0 + 0) * OUTF + o] = A.x  + bb;
    y[(size_t)(t0 + 1) * OUTF + o] = A.y  + bb;
    y[(size_t)(t0 + 2) * OUTF + o] = A.z  + bb;
    y[(size_t)(t0 + 3) * OUTF + o] = A.w  + bb;
    y[(size_t)(t0 + 4) * OUTF + o] = Bv.x + bb;
    y[(size_t)(t0 + 5) * OUTF + o] = Bv.y + bb;
    y[(size_t)(t0 + 6) * OUTF + o] = Bv.z + bb;
    y[(size_t)(t0 + 7) * OUTF + o] = Bv.w + bb;
  }
}

extern "C" void kernel_launch(void* const* d_in, const int* in_sizes, int n_in,
                              void* d_out, int out_size, void* d_ws, size_t ws_size,
                              hipStream_t stream) {
  const float* x      = (const float*)d_in[0];
  const float* weight = (const float*)d_in[1];
  const float* bias   = (const float*)d_in[2];
  float*       y      = (float*)d_out;

  hipLaunchKernelGGL(topk_select, dim3(OUTF), dim3(256), 0, stream, weight);
  hipLaunchKernelGGL(spmm8, dim3(NTOK / 8), dim3(1024), 0, stream, x, bias, y);
}